// Round 5
// baseline (724.230 us; speedup 1.0000x reference)
//
#include <hip/hip_runtime.h>
#include <math.h>

#define BB_ 32   // batch
#define PP_ 24   // sentences
#define SS_ 48   // tokens
#define HH_ 512  // hidden
#define FF_ 64   // feature
#define DD_ 576  // H+F
#define G4_ 2048 // 4H

typedef __attribute__((ext_vector_type(8))) short short8;
typedef __attribute__((ext_vector_type(4))) float f32x4;

__device__ __forceinline__ float sigf(float x) { return 1.f / (1.f + expf(-x)); }

__device__ __forceinline__ unsigned short f2bf(float f) {
    unsigned int u = __float_as_uint(f);
    u += 0x7FFFu + ((u >> 16) & 1u);     // RNE
    return (unsigned short)(u >> 16);
}

// ---------------------------------------------------------------------------
// K0 "prep": fused one-time work. grid 1729 x 256.
//  blk [0,512):    Whh_f fp32 -> bf16 B-fragment order (131072 frag-ids)
//  blk [512,1664): Wih_f fp32 -> bf16 row-major (294912 float4 groups)
//  blk [1664,1728): zero AfA (h0 fragments)
//  blk 1728:       mask-dtype detect + zero barrier flags
// ---------------------------------------------------------------------------
__global__ void __launch_bounds__(256) prep_kernel(
        const float* __restrict__ Whh, unsigned short* __restrict__ Bf,
        const float* __restrict__ Wih, unsigned short* __restrict__ Wbf,
        float* __restrict__ AfA,
        const unsigned int* __restrict__ maskw, int* __restrict__ mode,
        int* __restrict__ flags)
{
    int blk = blockIdx.x, tid = threadIdx.x;
    if (blk < 512) {
        int idx = blk * 256 + tid;            // fragment id
        int lane = idx & 63;
        int ks = (idx >> 6) & 15;
        int ti = (idx >> 10) & 1;
        int nb = idx >> 11;
        int c = lane & 15, q = lane >> 4;
        int nrow = (ti * 2 + (c >> 3)) * HH_ + nb * 8 + (c & 7);
        int k0 = ks * 32 + q * 8;
        const float* src = Whh + (size_t)nrow * HH_ + k0;
        unsigned int w0 = (unsigned int)f2bf(src[0]) | ((unsigned int)f2bf(src[1]) << 16);
        unsigned int w1 = (unsigned int)f2bf(src[2]) | ((unsigned int)f2bf(src[3]) << 16);
        unsigned int w2 = (unsigned int)f2bf(src[4]) | ((unsigned int)f2bf(src[5]) << 16);
        unsigned int w3 = (unsigned int)f2bf(src[6]) | ((unsigned int)f2bf(src[7]) << 16);
        *(uint4*)(Bf + (size_t)idx * 8) = make_uint4(w0, w1, w2, w3);
    } else if (blk < 1664) {
        int i = (blk - 512) * 256 + tid;      // < 294912 exactly
        float4 v = ((const float4*)Wih)[i];
        ushort4 o;
        o.x = f2bf(v.x); o.y = f2bf(v.y); o.z = f2bf(v.z); o.w = f2bf(v.w);
        ((ushort4*)Wbf)[i] = o;
    } else if (blk < 1728) {
        int idx = (blk - 1664) * 256 + tid;   // < 16384
        if (idx < 8192) AfA[idx] = 0.f;       // 16384 bf16 zeros
    } else {
        __shared__ int s_u8, s_f32;
        if (tid == 0) { s_u8 = 0; s_f32 = 0; }
        __syncthreads();
        int u8 = 0, f32 = 0;
        for (int i = tid; i < 9216; i += 256) {
            unsigned int w = maskw[i];
            if (w == 0x3F800000u) f32 = 1;
            else if (w > 1u) u8 = 1;
        }
        if (u8) s_u8 = 1;
        if (f32) s_f32 = 1;
        if (tid < 64) flags[tid] = 0;
        __syncthreads();
        if (tid == 0) *mode = s_f32 ? 2 : (s_u8 ? 1 : 0);
    }
}

// ---------------------------------------------------------------------------
// K1 v2: attention + pooling, single HBM read of emb via 96 KB LDS staging.
// 768 blocks (b*P+p) x 256 thr, 1 block/CU (LDS-capped).
// ---------------------------------------------------------------------------
__global__ void __launch_bounds__(256) attn2_kernel(
        const int* __restrict__ x,
        const void* __restrict__ x_mask,
        const int* __restrict__ mode_p,
        const float* __restrict__ x_feature,
        const float* __restrict__ emb,
        const float* __restrict__ w_attn,
        const float* __restrict__ b_attn,
        float* __restrict__ seq)
{
    __shared__ float4 es4[SS_ * 128];     // 48 rows x 512 f = 96 KB
    __shared__ float sc_s[SS_], alpha_s[SS_], vld_s[SS_];
    __shared__ int idx_s[SS_];
    __shared__ unsigned char msk_s[SS_];
    float* esf = (float*)es4;
    int bp = blockIdx.x;
    int b = bp / PP_, p = bp % PP_;
    int tid = threadIdx.x;
    int wave = tid >> 6, lane = tid & 63;
    int mode = *mode_p;
    float bscal = b_attn[0];
    if (tid < SS_) {
        size_t i = (size_t)bp * SS_ + tid;
        idx_s[tid] = x[i];
        unsigned char mv;
        if (mode == 1)      mv = ((const unsigned char*)x_mask)[i];
        else if (mode == 2) mv = (((const float*)x_mask)[i] != 0.f);
        else                mv = (((const int*)x_mask)[i] != 0);
        msk_s[tid] = mv;
        vld_s[tid] = mv ? 0.f : 1.f;
    }
    __syncthreads();
    // stage: 96 half-rows, deep independent float4 pipeline
    for (int i = wave; i < 2 * SS_; i += 4) {
        int s = i >> 1, part = i & 1;
        const float4* er = (const float4*)(emb + (size_t)idx_s[s] * HH_);
        es4[s * 128 + part * 64 + lane] = er[part * 64 + lane];
    }
    __syncthreads();
    // scores from LDS (wave per row), w_attn held in regs
    float4 wa0 = ((const float4*)w_attn)[lane];
    float4 wa1 = ((const float4*)w_attn)[64 + lane];
    for (int s = wave; s < SS_; s += 4) {
        float4 v0 = es4[s * 128 + lane];
        float4 v1 = es4[s * 128 + 64 + lane];
        float acc = v0.x * wa0.x + v0.y * wa0.y + v0.z * wa0.z + v0.w * wa0.w
                  + v1.x * wa1.x + v1.y * wa1.y + v1.z * wa1.z + v1.w * wa1.w;
        #pragma unroll
        for (int off = 32; off > 0; off >>= 1) acc += __shfl_down(acc, off, 64);
        if (lane == 0) sc_s[s] = acc + bscal;
    }
    __syncthreads();
    if (tid == 0) {
        float m = -3.4e38f;
        for (int s = 0; s < SS_; ++s) if (!msk_s[s] && sc_s[s] > m) m = sc_s[s];
        float sum = 0.f;
        for (int s = 0; s < SS_; ++s) {
            float a = 0.f;
            if (!msk_s[s]) { a = expf(sc_s[s] - m); sum += a; }
            alpha_s[s] = a;
        }
        float inv = (sum > 0.f) ? (1.f / sum) : 0.f;
        for (int s = 0; s < SS_; ++s) alpha_s[s] *= inv;
    }
    __syncthreads();
    float acc0 = 0.f, acc1 = 0.f;
    #pragma unroll 8
    for (int s = 0; s < SS_; ++s) {
        float al = alpha_s[s];
        acc0 += al * esf[s * 512 + tid];
        acc1 += al * esf[s * 512 + 256 + tid];
    }
    float* orow = seq + ((size_t)p * BB_ + b) * DD_;
    orow[tid] = acc0;
    orow[tid + 256] = acc1;
    if (tid < FF_) {   // wave 0 exactly: uniform branch
        float accF = 0.f;
        for (int s = 0; s < SS_; ++s)
            accF += vld_s[s] * x_feature[((size_t)bp * SS_ + s) * FF_ + tid];
        orow[HH_ + tid] = accF;
    }
}

// ---------------------------------------------------------------------------
// K3: input-gate GEMM via MFMA bf16 (unchanged from R4).
// ---------------------------------------------------------------------------
__global__ void __launch_bounds__(256) in_gates_mfma_kernel(
        const float* __restrict__ A,
        const unsigned short* __restrict__ Wbf,
        const float* __restrict__ bih,
        const float* __restrict__ bhh,
        float* __restrict__ Cout)
{
    int tid = threadIdx.x, lane = tid & 63, w = tid >> 6;
    int m0 = blockIdx.y * 16;
    int nb = blockIdx.x * 128 + w * 32;
    int c = lane & 15, q = lane >> 4;
    const float* Ap = A + (size_t)(m0 + c) * DD_ + q * 8;
    const unsigned short* Bp0 = Wbf + (size_t)(nb + c) * DD_ + q * 8;
    const unsigned short* Bp1 = Bp0 + 16 * DD_;
    f32x4 acc0 = {0.f, 0.f, 0.f, 0.f}, acc1 = {0.f, 0.f, 0.f, 0.f};
    for (int k = 0; k < DD_; k += 32) {
        float4 alo = *(const float4*)(Ap + k);
        float4 ahi = *(const float4*)(Ap + k + 4);
        short8 a;
        a[0] = (short)f2bf(alo.x); a[1] = (short)f2bf(alo.y);
        a[2] = (short)f2bf(alo.z); a[3] = (short)f2bf(alo.w);
        a[4] = (short)f2bf(ahi.x); a[5] = (short)f2bf(ahi.y);
        a[6] = (short)f2bf(ahi.z); a[7] = (short)f2bf(ahi.w);
        short8 b0 = *(const short8*)(Bp0 + k);
        short8 b1 = *(const short8*)(Bp1 + k);
        acc0 = __builtin_amdgcn_mfma_f32_16x16x32_bf16(a, b0, acc0, 0, 0, 0);
        acc1 = __builtin_amdgcn_mfma_f32_16x16x32_bf16(a, b1, acc1, 0, 0, 0);
    }
    #pragma unroll
    for (int r = 0; r < 4; ++r) {
        int m = m0 + q * 4 + r;
        int n0 = nb + c, n1 = nb + 16 + c;
        Cout[(size_t)m * G4_ + n0] = acc0[r] + bih[n0] + bhh[n0];
        Cout[(size_t)m * G4_ + n1] = acc1[r] + bih[n1] + bhh[n1];
    }
}

// ---------------------------------------------------------------------------
// K2: backward LSTM single step (unchanged from R4).
// ---------------------------------------------------------------------------
__global__ void __launch_bounds__(256) bwd_last2_kernel(const float* __restrict__ seq,
        const int* __restrict__ lens,
        const float* __restrict__ Wih_b,
        const float* __restrict__ bih_b,
        const float* __restrict__ bhh_b,
        float* __restrict__ hb)
{
    __shared__ float xsT[DD_ * 33];
    __shared__ int pl[BB_];
    int tid = threadIdx.x;
    if (tid < BB_) pl[tid] = lens[tid] - 1;
    __syncthreads();
    for (int idx = tid; idx < BB_ * DD_; idx += 256) {
        int b2 = idx / DD_;
        int k = idx - b2 * DD_;
        xsT[k * 33 + b2] = seq[((size_t)pl[b2] * BB_ + b2) * DD_ + k];
    }
    __syncthreads();
    int b = tid & 31, ul = tid >> 5;
    int u = blockIdx.x * 8 + ul;
    const float* wi = Wih_b + (size_t)u * DD_;
    const float* wg = Wih_b + (size_t)(2 * HH_ + u) * DD_;
    const float* wo = Wih_b + (size_t)(3 * HH_ + u) * DD_;
    float gi = 0.f, gg = 0.f, go = 0.f;
    #pragma unroll 4
    for (int k = 0; k < DD_; k += 4) {
        float4 w1 = *(const float4*)(wi + k);
        float4 w2 = *(const float4*)(wg + k);
        float4 w3 = *(const float4*)(wo + k);
        float x0 = xsT[(k + 0) * 33 + b];
        float x1 = xsT[(k + 1) * 33 + b];
        float x2 = xsT[(k + 2) * 33 + b];
        float x3 = xsT[(k + 3) * 33 + b];
        gi += w1.x * x0 + w1.y * x1 + w1.z * x2 + w1.w * x3;
        gg += w2.x * x0 + w2.y * x1 + w2.z * x2 + w2.w * x3;
        go += w3.x * x0 + w3.y * x1 + w3.z * x2 + w3.w * x3;
    }
    gi += bih_b[u] + bhh_b[u];
    gg += bih_b[2 * HH_ + u] + bhh_b[2 * HH_ + u];
    go += bih_b[3 * HH_ + u] + bhh_b[3 * HH_ + u];
    float cc = sigf(gi) * tanhf(gg);   // c0 = 0
    hb[(size_t)b * HH_ + u] = sigf(go) * tanhf(cc);
}

// ---------------------------------------------------------------------------
// K4 v3: PERSISTENT forward LSTM — all 24 steps in one dispatch.
// 64 blocks x 256 thr (co-resident: 64 <= 256 CUs, small LDS/VGPR).
// B-fragments register-resident for all steps; c in one register/thread.
// Cross-block h exchange via double-buffered Afrag + flag barrier with
// device-scope fences (per-XCD L2 non-coherence).
// ---------------------------------------------------------------------------
__global__ void __launch_bounds__(256) lstm_persist_kernel(
        unsigned short* __restrict__ AfA, unsigned short* __restrict__ AfB,
        float* __restrict__ hbuf, const float* __restrict__ Ain,
        const unsigned short* __restrict__ Bfrag, int* __restrict__ flags)
{
    __shared__ float gl[32 * 33];
    int tid = threadIdx.x, lane = tid & 63, wv = tid >> 6;
    int mt = wv & 1, ti = wv >> 1;
    int nb = blockIdx.x;
    // load B fragments once (64 VGPRs)
    const short8* Bp = (const short8*)Bfrag + (((size_t)nb * 2 + ti) * 16) * 64 + lane;
    short8 bfr[16];
    #pragma unroll
    for (int ks = 0; ks < 16; ++ks) bfr[ks] = Bp[ks * 64];
    int c = lane & 15, q = lane >> 4;
    int g = ti * 2 + (c >> 3), ul = c & 7;
    // epilogue / cell-state ids
    int b2 = tid >> 3, u2 = tid & 7;
    int ug = nb * 8 + u2;
    int ks2 = ug >> 5, q2 = (ug >> 3) & 3, j2 = ug & 7;
    int lane2 = (b2 & 15) + 16 * q2;
    size_t aoff = ((((size_t)(b2 >> 4)) * 16 + ks2) * 64 + lane2) * 8 + j2;
    float creg = 0.f;
    for (int t = 0; t < PP_; ++t) {
        const unsigned short* Af = (t & 1) ? AfB : AfA;
        unsigned short* An       = (t & 1) ? AfA : AfB;
        const float* Ain_t = Ain + (size_t)t * BB_ * G4_;
        // issue Ain loads first (independent of h)
        float ainv[4];
        #pragma unroll
        for (int r = 0; r < 4; ++r)
            ainv[r] = Ain_t[(size_t)(mt * 16 + q * 4 + r) * G4_ + g * HH_ + nb * 8 + ul];
        const short8* Ap = (const short8*)Af + (size_t)(mt * 16) * 64 + lane;
        short8 a[16];
        #pragma unroll
        for (int ks = 0; ks < 16; ++ks) a[ks] = Ap[ks * 64];
        f32x4 acc = {0.f, 0.f, 0.f, 0.f};
        #pragma unroll
        for (int ks = 0; ks < 16; ++ks)
            acc = __builtin_amdgcn_mfma_f32_16x16x32_bf16(a[ks], bfr[ks], acc, 0, 0, 0);
        #pragma unroll
        for (int r = 0; r < 4; ++r) {
            float v = acc[r] + ainv[r];
            v = (g == 2) ? tanhf(v) : sigf(v);
            gl[(g * 8 + ul) * 33 + (mt * 16 + q * 4 + r)] = v;
        }
        __syncthreads();
        float iv = gl[(0  + u2) * 33 + b2];
        float fv = gl[(8  + u2) * 33 + b2];
        float gv = gl[(16 + u2) * 33 + b2];
        float ov = gl[(24 + u2) * 33 + b2];
        creg = fv * creg + iv * gv;
        float h = ov * tanhf(creg);
        if (t == PP_ - 1) {
            hbuf[(size_t)b2 * HH_ + ug] = h;   // kernel end makes this visible
        } else {
            An[aoff] = f2bf(h);
            __threadfence();                   // release my store device-wide
            __syncthreads();                   // whole block done + gl reads done
            if (tid < 64) {
                if (tid == 0)
                    __hip_atomic_store(&flags[nb], t + 1, __ATOMIC_RELEASE,
                                       __HIP_MEMORY_SCOPE_AGENT);
                int target = t + 1;
                while (true) {
                    int v = __hip_atomic_load(&flags[tid], __ATOMIC_ACQUIRE,
                                              __HIP_MEMORY_SCOPE_AGENT);
                    if (__all(v >= target)) break;
                    __builtin_amdgcn_s_sleep(1);
                }
            }
            __syncthreads();
            __threadfence();                   // acquire: invalidate stale caches
        }
    }
}

// ---------------------------------------------------------------------------
// K6: fused head, one block x 1024 thr. last tile (32x1024 fp32) in LDS.
// ---------------------------------------------------------------------------
__global__ void __launch_bounds__(1024) head_fused_kernel(
        const float* __restrict__ hf, const float* __restrict__ hbwd,
        const int* __restrict__ lens,
        const float* __restrict__ Wfc, const float* __restrict__ bfc,
        const float* __restrict__ gamma, const float* __restrict__ beta,
        float* __restrict__ out)
{
    __shared__ float tileL[32 * 1024];   // 128 KB
    __shared__ float lmask[BB_];
    __shared__ float part[1024];
    __shared__ float ys[16][33];
    __shared__ float cstat[16];
    int tid = threadIdx.x;
    if (tid < BB_) lmask[tid] = (lens[tid] == PP_) ? 1.f : 0.f;
    __syncthreads();
    for (int j = tid; j < 32 * 1024; j += 1024) {
        int bb = j >> 10, col = j & 1023;
        float v = (col < HH_) ? hf[(size_t)bb * HH_ + col]
                              : hbwd[(size_t)bb * HH_ + col - HH_];
        tileL[j] = v * lmask[bb];
    }
    __syncthreads();
    int outi = tid & 511, half = tid >> 9;
    int i = outi >> 4, o = outi & 15;
    const float* wrow = Wfc + (size_t)o * 1024;
    float acc = 0.f;
    for (int q = 0; q < 32; ++q) {
        int j = i * 32 + q;
        #pragma unroll
        for (int bb2 = 0; bb2 < 16; ++bb2) {
            int bb = half * 16 + bb2;
            acc += tileL[bb * 1024 + j] * wrow[q * 32 + bb];
        }
    }
    part[tid] = acc;
    __syncthreads();
    if (tid < 512) ys[o][i] = part[tid] + part[tid + 512] + bfc[o];
    __syncthreads();
    if (tid < 16) {
        float mean = 0.f;
        for (int ii = 0; ii < 32; ++ii) mean += ys[tid][ii];
        mean *= (1.f / 32.f);
        float var = 0.f;
        for (int ii = 0; ii < 32; ++ii) { float d = ys[tid][ii] - mean; var += d * d; }
        var *= (1.f / 32.f);
        float inv = 1.f / sqrtf(var + 1e-5f);
        float gmm = gamma[tid], bt = beta[tid];
        float mx = -3.4e38f;
        for (int ii = 0; ii < 32; ++ii) {
            float v = gmm * (ys[tid][ii] - mean) * inv + bt;
            v = fmaxf(v, 0.f);
            ys[tid][ii] = v;
            mx = fmaxf(mx, v);
        }
        float s = 0.f;
        for (int ii = 0; ii < 32; ++ii) s += expf(ys[tid][ii] - mx);
        cstat[tid] = mx + logf(s);
    }
    __syncthreads();
    if (tid < 512) out[tid] = ys[o][i] - cstat[o];
}

extern "C" void kernel_launch(void* const* d_in, const int* in_sizes, int n_in,
                              void* d_out, int out_size, void* d_ws, size_t ws_size,
                              hipStream_t stream) {
    const int* x            = (const int*)d_in[0];
    const void* xm          = d_in[1];
    const float* x_feature  = (const float*)d_in[2];
    const int* lens         = (const int*)d_in[3];
    const float* emb    = (const float*)d_in[6];
    const float* w_attn = (const float*)d_in[7];
    const float* b_attn = (const float*)d_in[8];
    const float* Wih_f  = (const float*)d_in[9];
    const float* Whh_f  = (const float*)d_in[10];
    const float* bih_f  = (const float*)d_in[11];
    const float* bhh_f  = (const float*)d_in[12];
    const float* Wih_b  = (const float*)d_in[13];
    const float* bih_b  = (const float*)d_in[15];
    const float* bhh_b  = (const float*)d_in[16];
    const float* Wfc    = (const float*)d_in[17];
    const float* bfc    = (const float*)d_in[18];
    const float* gamma  = (const float*)d_in[19];
    const float* beta   = (const float*)d_in[20];

    float* ws    = (float*)d_ws;
    float* seq   = ws;                                    // 442368
    float* Ain   = seq + (size_t)PP_ * BB_ * DD_;         // 1572864
    float* hb    = Ain + (size_t)PP_ * BB_ * G4_;         // 16384
    float* hbuf  = hb + (size_t)BB_ * HH_;                // 16384
    float* AfA   = hbuf + (size_t)BB_ * HH_;              // 8192 (16384 bf16)
    float* AfB   = AfA + 8192;                            // 8192
    float* Bfrag = AfB + 8192;                            // 524288 (1M bf16)
    float* Wbf   = Bfrag + 524288;                        // 589824 (1.18M bf16)
    int*  flags  = (int*)(Wbf + 589824);                  // 64
    int*  mflag  = flags + 64;                            // 1

    float* outp = (float*)d_out;

    prep_kernel<<<dim3(1729), dim3(256), 0, stream>>>(
        Whh_f, (unsigned short*)Bfrag, Wih_f, (unsigned short*)Wbf,
        AfA, (const unsigned int*)xm, mflag, flags);
    attn2_kernel<<<dim3(BB_ * PP_), dim3(256), 0, stream>>>(
        x, xm, mflag, x_feature, emb, w_attn, b_attn, seq);
    in_gates_mfma_kernel<<<dim3(16, 48), dim3(256), 0, stream>>>(
        seq, (const unsigned short*)Wbf, bih_f, bhh_f, Ain);
    bwd_last2_kernel<<<dim3(64), dim3(256), 0, stream>>>(
        seq, lens, Wih_b, bih_b, bhh_b, hb);
    lstm_persist_kernel<<<dim3(64), dim3(256), 0, stream>>>(
        (unsigned short*)AfA, (unsigned short*)AfB, hbuf, Ain,
        (const unsigned short*)Bfrag, flags);
    head_fused_kernel<<<dim3(1), dim3(1024), 0, stream>>>(
        hbuf, hb, lens, Wfc, bfc, gamma, beta, outp);
}

// Round 6
// 491.681 us; speedup vs baseline: 1.4730x; 1.4730x over previous
//
#include <hip/hip_runtime.h>
#include <math.h>

#define BB_ 32   // batch
#define PP_ 24   // sentences
#define SS_ 48   // tokens
#define HH_ 512  // hidden
#define FF_ 64   // feature
#define DD_ 576  // H+F
#define G4_ 2048 // 4H

typedef __attribute__((ext_vector_type(8))) short short8;
typedef __attribute__((ext_vector_type(4))) float f32x4;

__device__ __forceinline__ float sigf(float x) { return 1.f / (1.f + expf(-x)); }

__device__ __forceinline__ unsigned short f2bf(float f) {
    unsigned int u = __float_as_uint(f);
    u += 0x7FFFu + ((u >> 16) & 1u);     // RNE
    return (unsigned short)(u >> 16);
}

// ---------------------------------------------------------------------------
// K0 "prep": fused one-time work. grid 1729 x 256.
//  blk [0,512):    Whh_f fp32 -> bf16 B-fragment order
//  blk [512,1664): Wih_f fp32 -> bf16 row-major
//  blk [1664,1728): zero AfA (h0 fragments)
//  blk 1728:       mask-dtype detect + zero barrier flags
// ---------------------------------------------------------------------------
__global__ void __launch_bounds__(256) prep_kernel(
        const float* __restrict__ Whh, unsigned short* __restrict__ Bf,
        const float* __restrict__ Wih, unsigned short* __restrict__ Wbf,
        float* __restrict__ AfA,
        const unsigned int* __restrict__ maskw, int* __restrict__ mode,
        int* __restrict__ flags)
{
    int blk = blockIdx.x, tid = threadIdx.x;
    if (blk < 512) {
        int idx = blk * 256 + tid;            // fragment id
        int lane = idx & 63;
        int ks = (idx >> 6) & 15;
        int ti = (idx >> 10) & 1;
        int nb = idx >> 11;
        int c = lane & 15, q = lane >> 4;
        int nrow = (ti * 2 + (c >> 3)) * HH_ + nb * 8 + (c & 7);
        int k0 = ks * 32 + q * 8;
        const float* src = Whh + (size_t)nrow * HH_ + k0;
        unsigned int w0 = (unsigned int)f2bf(src[0]) | ((unsigned int)f2bf(src[1]) << 16);
        unsigned int w1 = (unsigned int)f2bf(src[2]) | ((unsigned int)f2bf(src[3]) << 16);
        unsigned int w2 = (unsigned int)f2bf(src[4]) | ((unsigned int)f2bf(src[5]) << 16);
        unsigned int w3 = (unsigned int)f2bf(src[6]) | ((unsigned int)f2bf(src[7]) << 16);
        *(uint4*)(Bf + (size_t)idx * 8) = make_uint4(w0, w1, w2, w3);
    } else if (blk < 1664) {
        int i = (blk - 512) * 256 + tid;      // < 294912 exactly
        float4 v = ((const float4*)Wih)[i];
        ushort4 o;
        o.x = f2bf(v.x); o.y = f2bf(v.y); o.z = f2bf(v.z); o.w = f2bf(v.w);
        ((ushort4*)Wbf)[i] = o;
    } else if (blk < 1728) {
        int idx = (blk - 1664) * 256 + tid;   // < 16384
        if (idx < 8192) AfA[idx] = 0.f;       // 16384 bf16 zeros
    } else {
        __shared__ int s_u8, s_f32;
        if (tid == 0) { s_u8 = 0; s_f32 = 0; }
        __syncthreads();
        int u8 = 0, f32 = 0;
        for (int i = tid; i < 9216; i += 256) {
            unsigned int w = maskw[i];
            if (w == 0x3F800000u) f32 = 1;
            else if (w > 1u) u8 = 1;
        }
        if (u8) s_u8 = 1;
        if (f32) s_f32 = 1;
        if (tid < 64) flags[tid] = 0;
        __syncthreads();
        if (tid == 0) *mode = s_f32 ? 2 : (s_u8 ? 1 : 0);
    }
}

// ---------------------------------------------------------------------------
// K1: attention + weighted pooling -> seq [P][B][D]. Branch-free weighted
// sum (alpha=0 for masked rows) so the 48 row-loads pipeline.
// ---------------------------------------------------------------------------
__global__ void attn_rep_kernel(const int* __restrict__ x,
                                const void* __restrict__ x_mask,
                                const int* __restrict__ mode_p,
                                const float* __restrict__ x_feature,
                                const float* __restrict__ emb,
                                const float* __restrict__ w_attn,
                                const float* __restrict__ b_attn,
                                float* __restrict__ seq)
{
    int bp = blockIdx.x;              // b*P + p
    int b = bp / PP_, p = bp % PP_;
    int tid = threadIdx.x;            // 256
    __shared__ float wattn_s[HH_];
    __shared__ float sc_s[SS_];
    __shared__ float alpha_s[SS_];
    __shared__ int idx_s[SS_];
    __shared__ unsigned char msk_s[SS_];
    int mode = *mode_p;
    wattn_s[tid] = w_attn[tid];
    wattn_s[tid + 256] = w_attn[tid + 256];
    if (tid < SS_) {
        size_t i = (size_t)bp * SS_ + tid;
        idx_s[tid] = x[i];
        unsigned char mv;
        if (mode == 1)      mv = ((const unsigned char*)x_mask)[i];
        else if (mode == 2) mv = (((const float*)x_mask)[i] != 0.f);
        else                mv = (((const int*)x_mask)[i] != 0);
        msk_s[tid] = mv;
    }
    __syncthreads();
    int wave = tid >> 6, lane = tid & 63;
    for (int s = wave; s < SS_; s += 4) {
        const float* er = emb + (size_t)idx_s[s] * HH_;
        float acc = 0.f;
        #pragma unroll
        for (int j = 0; j < 8; ++j) {
            int d = lane * 8 + j;
            acc += er[d] * wattn_s[d];
        }
        #pragma unroll
        for (int off = 32; off > 0; off >>= 1) acc += __shfl_down(acc, off, 64);
        if (lane == 0) sc_s[s] = acc + b_attn[0];
    }
    __syncthreads();
    if (tid == 0) {
        float m = -3.4e38f;
        for (int s = 0; s < SS_; ++s) if (!msk_s[s] && sc_s[s] > m) m = sc_s[s];
        float sum = 0.f;
        for (int s = 0; s < SS_; ++s) {
            float a = 0.f;
            if (!msk_s[s]) { a = expf(sc_s[s] - m); sum += a; }
            alpha_s[s] = a;
        }
        float inv = (sum > 0.f) ? (1.f / sum) : 0.f;
        for (int s = 0; s < SS_; ++s) alpha_s[s] *= inv;
    }
    __syncthreads();
    float acc0 = 0.f, acc1 = 0.f;
    #pragma unroll 6
    for (int s = 0; s < SS_; ++s) {     // branch-free: masked rows have a=0
        float a = alpha_s[s];
        const float* er = emb + (size_t)idx_s[s] * HH_;
        acc0 += a * er[tid];
        acc1 += a * er[tid + 256];
    }
    float* orow = seq + ((size_t)p * BB_ + b) * DD_;
    orow[tid] = acc0;
    orow[tid + 256] = acc1;
    if (tid < FF_) {
        float acc2 = 0.f;
        for (int s = 0; s < SS_; ++s)
            if (!msk_s[s]) acc2 += x_feature[((size_t)bp * SS_ + s) * FF_ + tid];
        orow[HH_ + tid] = acc2;
    }
}

// ---------------------------------------------------------------------------
// K3: input-gate GEMM via MFMA bf16 (unchanged).
// ---------------------------------------------------------------------------
__global__ void __launch_bounds__(256) in_gates_mfma_kernel(
        const float* __restrict__ A,
        const unsigned short* __restrict__ Wbf,
        const float* __restrict__ bih,
        const float* __restrict__ bhh,
        float* __restrict__ Cout)
{
    int tid = threadIdx.x, lane = tid & 63, w = tid >> 6;
    int m0 = blockIdx.y * 16;
    int nb = blockIdx.x * 128 + w * 32;
    int c = lane & 15, q = lane >> 4;
    const float* Ap = A + (size_t)(m0 + c) * DD_ + q * 8;
    const unsigned short* Bp0 = Wbf + (size_t)(nb + c) * DD_ + q * 8;
    const unsigned short* Bp1 = Bp0 + 16 * DD_;
    f32x4 acc0 = {0.f, 0.f, 0.f, 0.f}, acc1 = {0.f, 0.f, 0.f, 0.f};
    for (int k = 0; k < DD_; k += 32) {
        float4 alo = *(const float4*)(Ap + k);
        float4 ahi = *(const float4*)(Ap + k + 4);
        short8 a;
        a[0] = (short)f2bf(alo.x); a[1] = (short)f2bf(alo.y);
        a[2] = (short)f2bf(alo.z); a[3] = (short)f2bf(alo.w);
        a[4] = (short)f2bf(ahi.x); a[5] = (short)f2bf(ahi.y);
        a[6] = (short)f2bf(ahi.z); a[7] = (short)f2bf(ahi.w);
        short8 b0 = *(const short8*)(Bp0 + k);
        short8 b1 = *(const short8*)(Bp1 + k);
        acc0 = __builtin_amdgcn_mfma_f32_16x16x32_bf16(a, b0, acc0, 0, 0, 0);
        acc1 = __builtin_amdgcn_mfma_f32_16x16x32_bf16(a, b1, acc1, 0, 0, 0);
    }
    #pragma unroll
    for (int r = 0; r < 4; ++r) {
        int m = m0 + q * 4 + r;
        int n0 = nb + c, n1 = nb + 16 + c;
        Cout[(size_t)m * G4_ + n0] = acc0[r] + bih[n0] + bhh[n0];
        Cout[(size_t)m * G4_ + n1] = acc1[r] + bih[n1] + bhh[n1];
    }
}

// ---------------------------------------------------------------------------
// K2: backward LSTM single step (unchanged).
// ---------------------------------------------------------------------------
__global__ void __launch_bounds__(256) bwd_last2_kernel(const float* __restrict__ seq,
        const int* __restrict__ lens,
        const float* __restrict__ Wih_b,
        const float* __restrict__ bih_b,
        const float* __restrict__ bhh_b,
        float* __restrict__ hb)
{
    __shared__ float xsT[DD_ * 33];
    __shared__ int pl[BB_];
    int tid = threadIdx.x;
    if (tid < BB_) pl[tid] = lens[tid] - 1;
    __syncthreads();
    for (int idx = tid; idx < BB_ * DD_; idx += 256) {
        int b2 = idx / DD_;
        int k = idx - b2 * DD_;
        xsT[k * 33 + b2] = seq[((size_t)pl[b2] * BB_ + b2) * DD_ + k];
    }
    __syncthreads();
    int b = tid & 31, ul = tid >> 5;
    int u = blockIdx.x * 8 + ul;
    const float* wi = Wih_b + (size_t)u * DD_;
    const float* wg = Wih_b + (size_t)(2 * HH_ + u) * DD_;
    const float* wo = Wih_b + (size_t)(3 * HH_ + u) * DD_;
    float gi = 0.f, gg = 0.f, go = 0.f;
    #pragma unroll 4
    for (int k = 0; k < DD_; k += 4) {
        float4 w1 = *(const float4*)(wi + k);
        float4 w2 = *(const float4*)(wg + k);
        float4 w3 = *(const float4*)(wo + k);
        float x0 = xsT[(k + 0) * 33 + b];
        float x1 = xsT[(k + 1) * 33 + b];
        float x2 = xsT[(k + 2) * 33 + b];
        float x3 = xsT[(k + 3) * 33 + b];
        gi += w1.x * x0 + w1.y * x1 + w1.z * x2 + w1.w * x3;
        gg += w2.x * x0 + w2.y * x1 + w2.z * x2 + w2.w * x3;
        go += w3.x * x0 + w3.y * x1 + w3.z * x2 + w3.w * x3;
    }
    gi += bih_b[u] + bhh_b[u];
    gg += bih_b[2 * HH_ + u] + bhh_b[2 * HH_ + u];
    go += bih_b[3 * HH_ + u] + bhh_b[3 * HH_ + u];
    float cc = sigf(gi) * tanhf(gg);   // c0 = 0
    hb[(size_t)b * HH_ + u] = sigf(go) * tanhf(cc);
}

// ---------------------------------------------------------------------------
// K4 v4: PERSISTENT forward LSTM, invalidate-free barrier.
// h exchange: sc1 (device-coherent) RELAXED atomic stores/loads meeting at
// the Infinity Cache — per-XCD L2 never invalidated, Ain/Bfrag stay cached.
// Release ordering: __syncthreads() drains vmcnt(0) (all lanes' h stores at
// coherence point) BEFORE tid0's relaxed flag store. Readers poll relaxed.
// ---------------------------------------------------------------------------
__global__ void __launch_bounds__(256) lstm_persist_kernel(
        unsigned short* __restrict__ AfA, unsigned short* __restrict__ AfB,
        float* __restrict__ hbuf, const float* __restrict__ Ain,
        const unsigned short* __restrict__ Bfrag, int* __restrict__ flags)
{
    __shared__ float gl[32 * 33];
    __shared__ unsigned short hstage[256];
    int tid = threadIdx.x, lane = tid & 63, wv = tid >> 6;
    int mt = wv & 1, ti = wv >> 1;
    int nb = blockIdx.x;
    // load B fragments once, register-resident for all 24 steps
    const short8* Bp = (const short8*)Bfrag + (((size_t)nb * 2 + ti) * 16) * 64 + lane;
    short8 bfr[16];
    #pragma unroll
    for (int ks = 0; ks < 16; ++ks) bfr[ks] = Bp[ks * 64];
    int c = lane & 15, q = lane >> 4;
    int g = ti * 2 + (c >> 3), ul = c & 7;
    int b2 = tid >> 3, u2 = tid & 7;
    int ug = nb * 8 + u2;
    float creg = 0.f;
    for (int t = 0; t < PP_; ++t) {
        const unsigned short* Af = (t & 1) ? AfB : AfA;
        unsigned short* An       = (t & 1) ? AfA : AfB;
        const float* Ain_t = Ain + (size_t)t * BB_ * G4_;
        float ainv[4];
        #pragma unroll
        for (int r = 0; r < 4; ++r)
            ainv[r] = Ain_t[(size_t)(mt * 16 + q * 4 + r) * G4_ + g * HH_ + nb * 8 + ul];
        // A fragments: device-coherent relaxed 8B loads (bypass local L2)
        const unsigned long long* Ap64 =
            (const unsigned long long*)Af + ((size_t)(mt * 16) * 64 + lane) * 2;
        short8 a[16];
        #pragma unroll
        for (int ks = 0; ks < 16; ++ks) {
            unsigned long long lo = __hip_atomic_load(Ap64 + (size_t)ks * 128,
                    __ATOMIC_RELAXED, __HIP_MEMORY_SCOPE_AGENT);
            unsigned long long hi = __hip_atomic_load(Ap64 + (size_t)ks * 128 + 1,
                    __ATOMIC_RELAXED, __HIP_MEMORY_SCOPE_AGENT);
            union { unsigned long long u[2]; short8 s; } cv;
            cv.u[0] = lo; cv.u[1] = hi;
            a[ks] = cv.s;
        }
        f32x4 acc = {0.f, 0.f, 0.f, 0.f};
        #pragma unroll
        for (int ks = 0; ks < 16; ++ks)
            acc = __builtin_amdgcn_mfma_f32_16x16x32_bf16(a[ks], bfr[ks], acc, 0, 0, 0);
        #pragma unroll
        for (int r = 0; r < 4; ++r) {
            float v = acc[r] + ainv[r];
            v = (g == 2) ? tanhf(v) : sigf(v);
            gl[(g * 8 + ul) * 33 + (mt * 16 + q * 4 + r)] = v;
        }
        __syncthreads();
        float iv = gl[(0  + u2) * 33 + b2];
        float fv = gl[(8  + u2) * 33 + b2];
        float gv = gl[(16 + u2) * 33 + b2];
        float ov = gl[(24 + u2) * 33 + b2];
        creg = fv * creg + iv * gv;
        float h = ov * tanhf(creg);
        if (t == PP_ - 1) {
            hbuf[(size_t)b2 * HH_ + ug] = h;   // kernel-end release handles this
        } else {
            hstage[tid] = f2bf(h);             // ordered by (b2*8 + u2)
            __syncthreads();                   // hstage ready; gl reads done
            if (tid < 64) {
                int b2s = tid >> 1, hf2 = tid & 1;
                const unsigned short* hp = &hstage[b2s * 8 + hf2 * 4];
                unsigned long long v = (unsigned long long)hp[0]
                                     | ((unsigned long long)hp[1] << 16)
                                     | ((unsigned long long)hp[2] << 32)
                                     | ((unsigned long long)hp[3] << 48);
                // ushort index of (b2s, u2=hf2*4): frag layout, 16B-contig per b2s
                size_t ub = ((((size_t)(b2s >> 4)) * 16 + (nb >> 2)) * 64
                             + ((b2s & 15) + 16 * (nb & 3))) * 8 + hf2 * 4;
                __hip_atomic_store((unsigned long long*)(An + ub), v,
                                   __ATOMIC_RELAXED, __HIP_MEMORY_SCOPE_AGENT);
            }
            __syncthreads();   // vmcnt(0) drain: all h stores at coherence point
            if (tid == 0)
                __hip_atomic_store(&flags[nb], t + 1,
                                   __ATOMIC_RELAXED, __HIP_MEMORY_SCOPE_AGENT);
            if (tid < 64) {
                int target = t + 1;
                while (true) {
                    int v = __hip_atomic_load(&flags[tid],
                            __ATOMIC_RELAXED, __HIP_MEMORY_SCOPE_AGENT);
                    if (__all(v >= target)) break;
                    __builtin_amdgcn_s_sleep(2);
                }
            }
            __syncthreads();
        }
    }
}

// ---------------------------------------------------------------------------
// K6: fused head, one block x 1024 thr (unchanged).
// ---------------------------------------------------------------------------
__global__ void __launch_bounds__(1024) head_fused_kernel(
        const float* __restrict__ hf, const float* __restrict__ hbwd,
        const int* __restrict__ lens,
        const float* __restrict__ Wfc, const float* __restrict__ bfc,
        const float* __restrict__ gamma, const float* __restrict__ beta,
        float* __restrict__ out)
{
    __shared__ float tileL[32 * 1024];   // 128 KB
    __shared__ float lmask[BB_];
    __shared__ float part[1024];
    __shared__ float ys[16][33];
    __shared__ float cstat[16];
    int tid = threadIdx.x;
    if (tid < BB_) lmask[tid] = (lens[tid] == PP_) ? 1.f : 0.f;
    __syncthreads();
    for (int j = tid; j < 32 * 1024; j += 1024) {
        int bb = j >> 10, col = j & 1023;
        float v = (col < HH_) ? hf[(size_t)bb * HH_ + col]
                              : hbwd[(size_t)bb * HH_ + col - HH_];
        tileL[j] = v * lmask[bb];
    }
    __syncthreads();
    int outi = tid & 511, half = tid >> 9;
    int i = outi >> 4, o = outi & 15;
    const float* wrow = Wfc + (size_t)o * 1024;
    float acc = 0.f;
    for (int q = 0; q < 32; ++q) {
        int j = i * 32 + q;
        #pragma unroll
        for (int bb2 = 0; bb2 < 16; ++bb2) {
            int bb = half * 16 + bb2;
            acc += tileL[bb * 1024 + j] * wrow[q * 32 + bb];
        }
    }
    part[tid] = acc;
    __syncthreads();
    if (tid < 512) ys[o][i] = part[tid] + part[tid + 512] + bfc[o];
    __syncthreads();
    if (tid < 16) {
        float mean = 0.f;
        for (int ii = 0; ii < 32; ++ii) mean += ys[tid][ii];
        mean *= (1.f / 32.f);
        float var = 0.f;
        for (int ii = 0; ii < 32; ++ii) { float d = ys[tid][ii] - mean; var += d * d; }
        var *= (1.f / 32.f);
        float inv = 1.f / sqrtf(var + 1e-5f);
        float gmm = gamma[tid], bt = beta[tid];
        float mx = -3.4e38f;
        for (int ii = 0; ii < 32; ++ii) {
            float v = gmm * (ys[tid][ii] - mean) * inv + bt;
            v = fmaxf(v, 0.f);
            ys[tid][ii] = v;
            mx = fmaxf(mx, v);
        }
        float s = 0.f;
        for (int ii = 0; ii < 32; ++ii) s += expf(ys[tid][ii] - mx);
        cstat[tid] = mx + logf(s);
    }
    __syncthreads();
    if (tid < 512) out[tid] = ys[o][i] - cstat[o];
}

extern "C" void kernel_launch(void* const* d_in, const int* in_sizes, int n_in,
                              void* d_out, int out_size, void* d_ws, size_t ws_size,
                              hipStream_t stream) {
    const int* x            = (const int*)d_in[0];
    const void* xm          = d_in[1];
    const float* x_feature  = (const float*)d_in[2];
    const int* lens         = (const int*)d_in[3];
    const float* emb    = (const float*)d_in[6];
    const float* w_attn = (const float*)d_in[7];
    const float* b_attn = (const float*)d_in[8];
    const float* Wih_f  = (const float*)d_in[9];
    const float* Whh_f  = (const float*)d_in[10];
    const float* bih_f  = (const float*)d_in[11];
    const float* bhh_f  = (const float*)d_in[12];
    const float* Wih_b  = (const float*)d_in[13];
    const float* bih_b  = (const float*)d_in[15];
    const float* bhh_b  = (const float*)d_in[16];
    const float* Wfc    = (const float*)d_in[17];
    const float* bfc    = (const float*)d_in[18];
    const float* gamma  = (const float*)d_in[19];
    const float* beta   = (const float*)d_in[20];

    float* ws    = (float*)d_ws;
    float* seq   = ws;                                    // 442368
    float* Ain   = seq + (size_t)PP_ * BB_ * DD_;         // 1572864
    float* hb    = Ain + (size_t)PP_ * BB_ * G4_;         // 16384
    float* hbuf  = hb + (size_t)BB_ * HH_;                // 16384
    float* AfA   = hbuf + (size_t)BB_ * HH_;              // 8192 (16384 bf16)
    float* AfB   = AfA + 8192;                            // 8192
    float* Bfrag = AfB + 8192;                            // 524288 (1M bf16)
    float* Wbf   = Bfrag + 524288;                        // 589824 (1.18M bf16)
    int*  flags  = (int*)(Wbf + 589824);                  // 64
    int*  mflag  = flags + 64;                            // 1

    float* outp = (float*)d_out;

    prep_kernel<<<dim3(1729), dim3(256), 0, stream>>>(
        Whh_f, (unsigned short*)Bfrag, Wih_f, (unsigned short*)Wbf,
        AfA, (const unsigned int*)xm, mflag, flags);
    attn_rep_kernel<<<dim3(BB_ * PP_), dim3(256), 0, stream>>>(
        x, xm, mflag, x_feature, emb, w_attn, b_attn, seq);
    in_gates_mfma_kernel<<<dim3(16, 48), dim3(256), 0, stream>>>(
        seq, (const unsigned short*)Wbf, bih_f, bhh_f, Ain);
    bwd_last2_kernel<<<dim3(64), dim3(256), 0, stream>>>(
        seq, lens, Wih_b, bih_b, bhh_b, hb);
    lstm_persist_kernel<<<dim3(64), dim3(256), 0, stream>>>(
        (unsigned short*)AfA, (unsigned short*)AfB, hbuf, Ain,
        (const unsigned short*)Bfrag, flags);
    head_fused_kernel<<<dim3(1), dim3(1024), 0, stream>>>(
        hbuf, hb, lens, Wfc, bfc, gamma, beta, outp);
}

// Round 7
// 441.161 us; speedup vs baseline: 1.6416x; 1.1145x over previous
//
#include <hip/hip_runtime.h>
#include <math.h>

#define BB_ 32   // batch
#define PP_ 24   // sentences
#define SS_ 48   // tokens
#define HH_ 512  // hidden
#define FF_ 64   // feature
#define DD_ 576  // H+F
#define G4_ 2048 // 4H

typedef __attribute__((ext_vector_type(8))) short short8;
typedef __attribute__((ext_vector_type(4))) float f32x4;

__device__ __forceinline__ float sigf(float x) { return 1.f / (1.f + expf(-x)); }

__device__ __forceinline__ unsigned short f2bf(float f) {
    unsigned int u = __float_as_uint(f);
    u += 0x7FFFu + ((u >> 16) & 1u);     // RNE
    return (unsigned short)(u >> 16);
}

// ---------------------------------------------------------------------------
// LAUNCH 1: fused [attn | weight prep | zeroing]. grid 2465 x 256.
//  blk [0,768):     attention+pooling (inline mask-dtype detect, valid-token
//                   compaction: masked rows never touch HBM)
//  blk [768,1280):  Whh_f -> bf16 B-fragment order
//  blk [1280,2432): Wih_f -> bf16 row-major
//  blk [2432,2464): zero AfA (h0 fragments)
//  blk 2464:        zero lstm barrier flags
// ---------------------------------------------------------------------------
__global__ void __launch_bounds__(256) prep_attn_kernel(
        const int* __restrict__ x, const unsigned int* __restrict__ maskw,
        const float* __restrict__ x_feature, const float* __restrict__ emb,
        const float* __restrict__ w_attn, const float* __restrict__ b_attn,
        const float* __restrict__ Whh, unsigned short* __restrict__ Bf,
        const float* __restrict__ Wih, unsigned short* __restrict__ Wbf,
        float* __restrict__ AfA, int* __restrict__ flags,
        float* __restrict__ seq)
{
    int blk = blockIdx.x, tid = threadIdx.x;
    if (blk < 768) {
        __shared__ float sc_s[SS_], alpha_s[SS_];
        __shared__ int vtok[SS_], vpos[SS_];
        __shared__ int nv_s, s_u8, s_f32;
        __shared__ int idx_s[SS_];
        __shared__ unsigned char msk_s[SS_];
        if (tid == 0) { s_u8 = 0; s_f32 = 0; }
        __syncthreads();
        int u8 = 0, f32 = 0;
        for (int i = tid; i < 9216; i += 256) {     // mask dtype detect (L2-hot)
            unsigned int w = maskw[i];
            if (w == 0x3F800000u) f32 = 1;
            else if (w > 1u) u8 = 1;
        }
        if (u8) s_u8 = 1;
        if (f32) s_f32 = 1;
        __syncthreads();
        int mode = s_f32 ? 2 : (s_u8 ? 1 : 0);
        int bp = blk, b = bp / PP_, p = bp % PP_;
        if (tid < SS_) {
            size_t i = (size_t)bp * SS_ + tid;
            idx_s[tid] = x[i];
            unsigned char mv;
            if (mode == 1)      mv = ((const unsigned char*)maskw)[i];
            else if (mode == 2) mv = (((const float*)maskw)[i] != 0.f);
            else                mv = (((const int*)maskw)[i] != 0);
            msk_s[tid] = mv;
        }
        __syncthreads();
        if (tid == 0) {                              // compact valid tokens
            int nv = 0;
            for (int s = 0; s < SS_; ++s)
                if (!msk_s[s]) { vtok[nv] = idx_s[s]; vpos[nv] = s; ++nv; }
            nv_s = nv;
        }
        __syncthreads();
        int nv = nv_s;
        int wave = tid >> 6, lane = tid & 63;
        float4 wa0 = ((const float4*)w_attn)[lane];        // regs, no LDS bank hits
        float4 wa1 = ((const float4*)w_attn)[64 + lane];
        for (int j = wave; j < nv; j += 4) {
            const float4* er4 = (const float4*)(emb + (size_t)vtok[j] * HH_);
            float4 v0 = er4[lane], v1 = er4[64 + lane];    // coalesced full row
            float acc = v0.x * wa0.x + v0.y * wa0.y + v0.z * wa0.z + v0.w * wa0.w
                      + v1.x * wa1.x + v1.y * wa1.y + v1.z * wa1.z + v1.w * wa1.w;
            #pragma unroll
            for (int off = 32; off > 0; off >>= 1) acc += __shfl_down(acc, off, 64);
            if (lane == 0) sc_s[j] = acc + b_attn[0];
        }
        __syncthreads();
        if (tid == 0) {                              // softmax over valid subset
            float m = -3.4e38f;
            for (int j = 0; j < nv; ++j) if (sc_s[j] > m) m = sc_s[j];
            float sum = 0.f;
            for (int j = 0; j < nv; ++j) { float a = expf(sc_s[j] - m); alpha_s[j] = a; sum += a; }
            float inv = (nv > 0) ? (1.f / sum) : 0.f;
            for (int j = 0; j < nv; ++j) alpha_s[j] *= inv;
        }
        __syncthreads();
        float acc0 = 0.f, acc1 = 0.f;
        for (int j = 0; j < nv; ++j) {               // branch-free, pipelines
            float a = alpha_s[j];
            const float* er = emb + (size_t)vtok[j] * HH_;
            acc0 += a * er[tid];
            acc1 += a * er[tid + 256];
        }
        float* orow = seq + ((size_t)p * BB_ + b) * DD_;
        orow[tid] = acc0;
        orow[tid + 256] = acc1;
        if (tid < FF_) {
            float accF = 0.f;
            for (int j = 0; j < nv; ++j)
                accF += x_feature[((size_t)bp * SS_ + vpos[j]) * FF_ + tid];
            orow[HH_ + tid] = accF;
        }
    } else if (blk < 1280) {
        int idx = (blk - 768) * 256 + tid;          // Whh -> B-fragment order
        int lane = idx & 63;
        int ks = (idx >> 6) & 15;
        int ti = (idx >> 10) & 1;
        int nb = idx >> 11;
        int c = lane & 15, q = lane >> 4;
        int nrow = (ti * 2 + (c >> 3)) * HH_ + nb * 8 + (c & 7);
        int k0 = ks * 32 + q * 8;
        const float* src = Whh + (size_t)nrow * HH_ + k0;
        unsigned int w0 = (unsigned int)f2bf(src[0]) | ((unsigned int)f2bf(src[1]) << 16);
        unsigned int w1 = (unsigned int)f2bf(src[2]) | ((unsigned int)f2bf(src[3]) << 16);
        unsigned int w2 = (unsigned int)f2bf(src[4]) | ((unsigned int)f2bf(src[5]) << 16);
        unsigned int w3 = (unsigned int)f2bf(src[6]) | ((unsigned int)f2bf(src[7]) << 16);
        *(uint4*)(Bf + (size_t)idx * 8) = make_uint4(w0, w1, w2, w3);
    } else if (blk < 2432) {
        int i = (blk - 1280) * 256 + tid;           // Wih -> bf16 (294912 x4)
        float4 v = ((const float4*)Wih)[i];
        ushort4 o;
        o.x = f2bf(v.x); o.y = f2bf(v.y); o.z = f2bf(v.z); o.w = f2bf(v.w);
        ((ushort4*)Wbf)[i] = o;
    } else if (blk < 2464) {
        int idx = (blk - 2432) * 256 + tid;
        if (idx < 8192) AfA[idx] = 0.f;             // h0 fragments = 0
    } else {
        if (tid < 64) flags[tid] = 0;
    }
}

// ---------------------------------------------------------------------------
// LAUNCH 2: input-gate GEMM via MFMA bf16 (unchanged math).
// ---------------------------------------------------------------------------
__global__ void __launch_bounds__(256) in_gates_mfma_kernel(
        const float* __restrict__ A,
        const unsigned short* __restrict__ Wbf,
        const float* __restrict__ bih,
        const float* __restrict__ bhh,
        float* __restrict__ Cout)
{
    int tid = threadIdx.x, lane = tid & 63, w = tid >> 6;
    int m0 = blockIdx.y * 16;
    int nb = blockIdx.x * 128 + w * 32;
    int c = lane & 15, q = lane >> 4;
    const float* Ap = A + (size_t)(m0 + c) * DD_ + q * 8;
    const unsigned short* Bp0 = Wbf + (size_t)(nb + c) * DD_ + q * 8;
    const unsigned short* Bp1 = Bp0 + 16 * DD_;
    f32x4 acc0 = {0.f, 0.f, 0.f, 0.f}, acc1 = {0.f, 0.f, 0.f, 0.f};
    for (int k = 0; k < DD_; k += 32) {
        float4 alo = *(const float4*)(Ap + k);
        float4 ahi = *(const float4*)(Ap + k + 4);
        short8 a;
        a[0] = (short)f2bf(alo.x); a[1] = (short)f2bf(alo.y);
        a[2] = (short)f2bf(alo.z); a[3] = (short)f2bf(alo.w);
        a[4] = (short)f2bf(ahi.x); a[5] = (short)f2bf(ahi.y);
        a[6] = (short)f2bf(ahi.z); a[7] = (short)f2bf(ahi.w);
        short8 b0 = *(const short8*)(Bp0 + k);
        short8 b1 = *(const short8*)(Bp1 + k);
        acc0 = __builtin_amdgcn_mfma_f32_16x16x32_bf16(a, b0, acc0, 0, 0, 0);
        acc1 = __builtin_amdgcn_mfma_f32_16x16x32_bf16(a, b1, acc1, 0, 0, 0);
    }
    #pragma unroll
    for (int r = 0; r < 4; ++r) {
        int m = m0 + q * 4 + r;
        int n0 = nb + c, n1 = nb + 16 + c;
        Cout[(size_t)m * G4_ + n0] = acc0[r] + bih[n0] + bhh[n0];
        Cout[(size_t)m * G4_ + n1] = acc1[r] + bih[n1] + bhh[n1];
    }
}

// ---------------------------------------------------------------------------
// LAUNCH 3: fused [persistent fwd LSTM | backward one-step]. grid 128 x 256.
//  blk [0,64):   persistent LSTM (sc1 relaxed h-exchange, flag barrier)
//  blk [64,128): backward-LSTM collapsed single step
// All 128 blocks co-resident (<=2 blocks/CU at 76 KB LDS) -> no deadlock.
// ---------------------------------------------------------------------------
__global__ void __launch_bounds__(256) lstm_bwd_kernel(
        unsigned short* __restrict__ AfA, unsigned short* __restrict__ AfB,
        float* __restrict__ hbuf, const float* __restrict__ Ain,
        const unsigned short* __restrict__ Bfrag, int* __restrict__ flags,
        const float* __restrict__ seq, const int* __restrict__ lens,
        const float* __restrict__ Wih_b, const float* __restrict__ bih_b,
        const float* __restrict__ bhh_b, float* __restrict__ hbw)
{
    __shared__ float smem[19040];   // union: lstm {gl 1056f + hstage} | bwd {xsT 19008f + pl}
    int tid = threadIdx.x;
    if (blockIdx.x < 64) {
        float* gl = smem;
        unsigned short* hstage = (unsigned short*)(smem + 1056);
        int lane = tid & 63, wv = tid >> 6;
        int mt = wv & 1, ti = wv >> 1;
        int nb = blockIdx.x;
        const short8* Bp = (const short8*)Bfrag + (((size_t)nb * 2 + ti) * 16) * 64 + lane;
        short8 bfr[16];
        #pragma unroll
        for (int ks = 0; ks < 16; ++ks) bfr[ks] = Bp[ks * 64];
        int c = lane & 15, q = lane >> 4;
        int g = ti * 2 + (c >> 3), ul = c & 7;
        int b2 = tid >> 3, u2 = tid & 7;
        int ug = nb * 8 + u2;
        float creg = 0.f;
        for (int t = 0; t < PP_; ++t) {
            const unsigned short* Af = (t & 1) ? AfB : AfA;
            unsigned short* An       = (t & 1) ? AfA : AfB;
            const float* Ain_t = Ain + (size_t)t * BB_ * G4_;
            float ainv[4];
            #pragma unroll
            for (int r = 0; r < 4; ++r)
                ainv[r] = Ain_t[(size_t)(mt * 16 + q * 4 + r) * G4_ + g * HH_ + nb * 8 + ul];
            const unsigned long long* Ap64 =
                (const unsigned long long*)Af + ((size_t)(mt * 16) * 64 + lane) * 2;
            short8 a[16];
            #pragma unroll
            for (int ks = 0; ks < 16; ++ks) {
                unsigned long long lo = __hip_atomic_load(Ap64 + (size_t)ks * 128,
                        __ATOMIC_RELAXED, __HIP_MEMORY_SCOPE_AGENT);
                unsigned long long hi = __hip_atomic_load(Ap64 + (size_t)ks * 128 + 1,
                        __ATOMIC_RELAXED, __HIP_MEMORY_SCOPE_AGENT);
                union { unsigned long long u[2]; short8 s; } cv;
                cv.u[0] = lo; cv.u[1] = hi;
                a[ks] = cv.s;
            }
            // two independent accumulator chains -> half the serial MFMA latency
            f32x4 acA = {0.f, 0.f, 0.f, 0.f}, acB = {0.f, 0.f, 0.f, 0.f};
            #pragma unroll
            for (int ks = 0; ks < 16; ks += 2) {
                acA = __builtin_amdgcn_mfma_f32_16x16x32_bf16(a[ks],     bfr[ks],     acA, 0, 0, 0);
                acB = __builtin_amdgcn_mfma_f32_16x16x32_bf16(a[ks + 1], bfr[ks + 1], acB, 0, 0, 0);
            }
            #pragma unroll
            for (int r = 0; r < 4; ++r) {
                float v = acA[r] + acB[r] + ainv[r];
                v = (g == 2) ? tanhf(v) : sigf(v);
                gl[(g * 8 + ul) * 33 + (mt * 16 + q * 4 + r)] = v;
            }
            __syncthreads();
            float iv = gl[(0  + u2) * 33 + b2];
            float fv = gl[(8  + u2) * 33 + b2];
            float gv = gl[(16 + u2) * 33 + b2];
            float ov = gl[(24 + u2) * 33 + b2];
            creg = fv * creg + iv * gv;
            float h = ov * tanhf(creg);
            if (t == PP_ - 1) {
                hbuf[(size_t)b2 * HH_ + ug] = h;
            } else {
                hstage[tid] = f2bf(h);
                __syncthreads();
                if (tid < 64) {
                    int b2s = tid >> 1, hf2 = tid & 1;
                    const unsigned short* hp = &hstage[b2s * 8 + hf2 * 4];
                    unsigned long long v = (unsigned long long)hp[0]
                                         | ((unsigned long long)hp[1] << 16)
                                         | ((unsigned long long)hp[2] << 32)
                                         | ((unsigned long long)hp[3] << 48);
                    size_t ub = ((((size_t)(b2s >> 4)) * 16 + (nb >> 2)) * 64
                                 + ((b2s & 15) + 16 * (nb & 3))) * 8 + hf2 * 4;
                    __hip_atomic_store((unsigned long long*)(An + ub), v,
                                       __ATOMIC_RELAXED, __HIP_MEMORY_SCOPE_AGENT);
                }
                __syncthreads();   // vmcnt(0): h stores at coherence point
                if (tid == 0)
                    __hip_atomic_store(&flags[nb], t + 1,
                                       __ATOMIC_RELAXED, __HIP_MEMORY_SCOPE_AGENT);
                if (tid < 64) {
                    int target = t + 1;
                    while (true) {
                        int v = __hip_atomic_load(&flags[tid],
                                __ATOMIC_RELAXED, __HIP_MEMORY_SCOPE_AGENT);
                        if (__all(v >= target)) break;
                        __builtin_amdgcn_s_sleep(1);
                    }
                }
                __syncthreads();
            }
        }
    } else {
        float* xsT = smem;
        int* pl = (int*)(smem + 19008);
        int blk2 = blockIdx.x - 64;
        if (tid < BB_) pl[tid] = lens[tid] - 1;
        __syncthreads();
        for (int idx = tid; idx < BB_ * DD_; idx += 256) {
            int b2 = idx / DD_;
            int k = idx - b2 * DD_;
            xsT[k * 33 + b2] = seq[((size_t)pl[b2] * BB_ + b2) * DD_ + k];
        }
        __syncthreads();
        int b = tid & 31, ul = tid >> 5;
        int u = blk2 * 8 + ul;
        const float* wi = Wih_b + (size_t)u * DD_;
        const float* wg = Wih_b + (size_t)(2 * HH_ + u) * DD_;
        const float* wo = Wih_b + (size_t)(3 * HH_ + u) * DD_;
        float gi = 0.f, gg = 0.f, go = 0.f;
        #pragma unroll 4
        for (int k = 0; k < DD_; k += 4) {
            float4 w1 = *(const float4*)(wi + k);
            float4 w2 = *(const float4*)(wg + k);
            float4 w3 = *(const float4*)(wo + k);
            float x0 = xsT[(k + 0) * 33 + b];
            float x1 = xsT[(k + 1) * 33 + b];
            float x2 = xsT[(k + 2) * 33 + b];
            float x3 = xsT[(k + 3) * 33 + b];
            gi += w1.x * x0 + w1.y * x1 + w1.z * x2 + w1.w * x3;
            gg += w2.x * x0 + w2.y * x1 + w2.z * x2 + w2.w * x3;
            go += w3.x * x0 + w3.y * x1 + w3.z * x2 + w3.w * x3;
        }
        gi += bih_b[u] + bhh_b[u];
        gg += bih_b[2 * HH_ + u] + bhh_b[2 * HH_ + u];
        go += bih_b[3 * HH_ + u] + bhh_b[3 * HH_ + u];
        float cc = sigf(gi) * tanhf(gg);   // c0 = 0
        hbw[(size_t)b * HH_ + u] = sigf(go) * tanhf(cc);
    }
}

// ---------------------------------------------------------------------------
// LAUNCH 4: fused head, one block x 1024 thr (unchanged).
// ---------------------------------------------------------------------------
__global__ void __launch_bounds__(1024) head_fused_kernel(
        const float* __restrict__ hf, const float* __restrict__ hbwd,
        const int* __restrict__ lens,
        const float* __restrict__ Wfc, const float* __restrict__ bfc,
        const float* __restrict__ gamma, const float* __restrict__ beta,
        float* __restrict__ out)
{
    __shared__ float tileL[32 * 1024];   // 128 KB
    __shared__ float lmask[BB_];
    __shared__ float part[1024];
    __shared__ float ys[16][33];
    __shared__ float cstat[16];
    int tid = threadIdx.x;
    if (tid < BB_) lmask[tid] = (lens[tid] == PP_) ? 1.f : 0.f;
    __syncthreads();
    for (int j = tid; j < 32 * 1024; j += 1024) {
        int bb = j >> 10, col = j & 1023;
        float v = (col < HH_) ? hf[(size_t)bb * HH_ + col]
                              : hbwd[(size_t)bb * HH_ + col - HH_];
        tileL[j] = v * lmask[bb];
    }
    __syncthreads();
    int outi = tid & 511, half = tid >> 9;
    int i = outi >> 4, o = outi & 15;
    const float* wrow = Wfc + (size_t)o * 1024;
    float acc = 0.f;
    for (int q = 0; q < 32; ++q) {
        int j = i * 32 + q;
        #pragma unroll
        for (int bb2 = 0; bb2 < 16; ++bb2) {
            int bb = half * 16 + bb2;
            acc += tileL[bb * 1024 + j] * wrow[q * 32 + bb];
        }
    }
    part[tid] = acc;
    __syncthreads();
    if (tid < 512) ys[o][i] = part[tid] + part[tid + 512] + bfc[o];
    __syncthreads();
    if (tid < 16) {
        float mean = 0.f;
        for (int ii = 0; ii < 32; ++ii) mean += ys[tid][ii];
        mean *= (1.f / 32.f);
        float var = 0.f;
        for (int ii = 0; ii < 32; ++ii) { float d = ys[tid][ii] - mean; var += d * d; }
        var *= (1.f / 32.f);
        float inv = 1.f / sqrtf(var + 1e-5f);
        float gmm = gamma[tid], bt = beta[tid];
        float mx = -3.4e38f;
        for (int ii = 0; ii < 32; ++ii) {
            float v = gmm * (ys[tid][ii] - mean) * inv + bt;
            v = fmaxf(v, 0.f);
            ys[tid][ii] = v;
            mx = fmaxf(mx, v);
        }
        float s = 0.f;
        for (int ii = 0; ii < 32; ++ii) s += expf(ys[tid][ii] - mx);
        cstat[tid] = mx + logf(s);
    }
    __syncthreads();
    if (tid < 512) out[tid] = ys[o][i] - cstat[o];
}

extern "C" void kernel_launch(void* const* d_in, const int* in_sizes, int n_in,
                              void* d_out, int out_size, void* d_ws, size_t ws_size,
                              hipStream_t stream) {
    const int* x            = (const int*)d_in[0];
    const void* xm          = d_in[1];
    const float* x_feature  = (const float*)d_in[2];
    const int* lens         = (const int*)d_in[3];
    const float* emb    = (const float*)d_in[6];
    const float* w_attn = (const float*)d_in[7];
    const float* b_attn = (const float*)d_in[8];
    const float* Wih_f  = (const float*)d_in[9];
    const float* Whh_f  = (const float*)d_in[10];
    const float* bih_f  = (const float*)d_in[11];
    const float* bhh_f  = (const float*)d_in[12];
    const float* Wih_b  = (const float*)d_in[13];
    const float* bih_b  = (const float*)d_in[15];
    const float* bhh_b  = (const float*)d_in[16];
    const float* Wfc    = (const float*)d_in[17];
    const float* bfc    = (const float*)d_in[18];
    const float* gamma  = (const float*)d_in[19];
    const float* beta   = (const float*)d_in[20];

    float* ws    = (float*)d_ws;
    float* seq   = ws;                                    // 442368
    float* Ain   = seq + (size_t)PP_ * BB_ * DD_;         // 1572864
    float* hb    = Ain + (size_t)PP_ * BB_ * G4_;         // 16384
    float* hbuf  = hb + (size_t)BB_ * HH_;                // 16384
    float* AfA   = hbuf + (size_t)BB_ * HH_;              // 8192 (16384 bf16)
    float* AfB   = AfA + 8192;                            // 8192
    float* Bfrag = AfB + 8192;                            // 524288 (1M bf16)
    float* Wbf   = Bfrag + 524288;                        // 589824 (1.18M bf16)
    int*  flags  = (int*)(Wbf + 589824);                  // 64

    float* outp = (float*)d_out;

    prep_attn_kernel<<<dim3(2465), dim3(256), 0, stream>>>(
        x, (const unsigned int*)xm, x_feature, emb, w_attn, b_attn,
        Whh_f, (unsigned short*)Bfrag, Wih_f, (unsigned short*)Wbf,
        AfA, flags, seq);
    in_gates_mfma_kernel<<<dim3(16, 48), dim3(256), 0, stream>>>(
        seq, (const unsigned short*)Wbf, bih_f, bhh_f, Ain);
    lstm_bwd_kernel<<<dim3(128), dim3(256), 0, stream>>>(
        (unsigned short*)AfA, (unsigned short*)AfB, hbuf, Ain,
        (const unsigned short*)Bfrag, flags,
        seq, lens, Wih_b, bih_b, bhh_b, hb);
    head_fused_kernel<<<dim3(1), dim3(1024), 0, stream>>>(
        hbuf, hb, lens, Wfc, bfc, gamma, beta, outp);
}